// Round 8
// baseline (297.350 us; speedup 1.0000x reference)
//
#include <hip/hip_runtime.h>

#define BB 32
#define NN 256
#define EE 300
#define HH 256
#define KK 8
#define MARGINF 0.2f
#define EP 320   // E padded for K-loop

typedef __attribute__((ext_vector_type(8))) short bf16x8;
typedef __attribute__((ext_vector_type(4))) float f32x4;
typedef __attribute__((ext_vector_type(16))) float f32x16;

__device__ inline ushort f2bf(float f) {
  unsigned u = __float_as_uint(f);
  u += 0x7fffu + ((u >> 16) & 1u);          // RNE
  return (ushort)(u >> 16);
}
__device__ inline float bf2f(ushort s) { return __uint_as_float(((unsigned)s) << 16); }
__device__ inline unsigned pack2bf(float f0, float f1) {   // [f0 lo | f1 hi], RNE
  unsigned u0 = __float_as_uint(f0); u0 += 0x7fffu + ((u0 >> 16) & 1u);
  unsigned u1 = __float_as_uint(f1); u1 += 0x7fffu + ((u1 >> 16) & 1u);
  return (u0 >> 16) | (u1 & 0xffff0000u);
}

// ---------------------------------------------------------------------------
// wconv: W_a2h/W_c2h fp32 [256][300] -> Wb bf16 [2][256][320] (zero-padded).
// ---------------------------------------------------------------------------
__global__ __launch_bounds__(256) void wconv_kernel(
    const float* __restrict__ Wa, const float* __restrict__ Wc,
    ushort* __restrict__ Wb)
{
  const int i = blockIdx.x * 256 + threadIdx.x;   // over 2*256*320 = 163840
  const int e = i % EP;
  const int hw = i / EP;
  const int h = hw & 255;
  const int w = hw >> 8;
  const float* src = w ? Wc : Wa;
  Wb[i] = (e < EE) ? f2bf(src[(size_t)h * EE + e]) : (ushort)0;
}

// ---------------------------------------------------------------------------
// proj v2 (unchanged from round 7): one WG per (which,b,32-row n-tile),
// X tile packed to LDS once (1 barrier), W B-frags straight from L2-hot bf16.
// ---------------------------------------------------------------------------
__global__ __launch_bounds__(256, 3) void proj_kernel(
    const float* __restrict__ he_a, const float* __restrict__ he_p,
    const float* __restrict__ he_n, const ushort* __restrict__ Wb,
    const float* __restrict__ b_a2h, const float* __restrict__ b_c2h,
    ushort* __restrict__ AT)
{
  const int z = blockIdx.y;           // 96 = 3*BB
  const int which = z >> 5;
  const int b = z & 31;
  const int n0 = blockIdx.x * 32;
  const int tid = threadIdx.x;
  const int wv = tid >> 6;
  const int lane = tid & 63;
  const int col = lane & 15;
  const int quad = lane >> 4;

  const float* X = (which == 0 ? he_a : which == 1 ? he_p : he_n) + (size_t)b * NN * EE;
  const ushort* W = Wb + (size_t)(which == 0 ? 0 : 1) * HH * EP;
  const float* bias = (which == 0 ? b_a2h : b_c2h);

  __shared__ __align__(16) ushort sX[32][328];
  __shared__ __align__(16) ushort tr[32][264];

  {
    const int row = tid >> 3, seg = tid & 7;
    const float* xr = X + (size_t)(n0 + row) * EE;
#pragma unroll
    for (int q = 0; q < 10; q++) {
      const int j = seg + 8 * q;
      float4 xv = {0.f, 0.f, 0.f, 0.f};
      if (j < 75) xv = *(const float4*)&xr[4 * j];
      uint2 p; p.x = pack2bf(xv.x, xv.y); p.y = pack2bf(xv.z, xv.w);
      *(uint2*)&sX[row][4 * j] = p;
    }
  }
  __syncthreads();

  f32x4 acc[2][4];
#pragma unroll
  for (int nf = 0; nf < 2; nf++)
#pragma unroll
    for (int mb = 0; mb < 4; mb++) acc[nf][mb] = (f32x4){0.f, 0.f, 0.f, 0.f};

#pragma unroll
  for (int ks = 0; ks < 10; ks++) {
    const int off = 32 * ks + 8 * quad;
    const bf16x8 a0 = *(const bf16x8*)&sX[col][off];
    const bf16x8 a1 = *(const bf16x8*)&sX[16 + col][off];
#pragma unroll
    for (int mb = 0; mb < 4; mb++) {
      const bf16x8 w8 = *(const bf16x8*)&W[(size_t)(64 * wv + 16 * mb + col) * EP + off];
      acc[0][mb] = __builtin_amdgcn_mfma_f32_16x16x32_bf16(a0, w8, acc[0][mb], 0, 0, 0);
      acc[1][mb] = __builtin_amdgcn_mfma_f32_16x16x32_bf16(a1, w8, acc[1][mb], 0, 0, 0);
    }
  }

#pragma unroll
  for (int nf = 0; nf < 2; nf++)
#pragma unroll
    for (int mb = 0; mb < 4; mb++) {
      const float bi = bias[64 * wv + 16 * mb + col];
#pragma unroll
      for (int r = 0; r < 4; r++)
        tr[16 * nf + 4 * quad + r][64 * wv + 16 * mb + col] = f2bf(acc[nf][mb][r] + bi);
    }
  __syncthreads();
  {
    const int row = tid >> 3, seg = tid & 7;
    ushort* dst = &AT[((size_t)(which * BB + b) * NN + n0 + row) * HH];
#pragma unroll
    for (int j = 0; j < 4; j++)
      *(uint4*)&dst[(seg * 4 + j) * 8] = *(const uint4*)&tr[row][(seg * 4 + j) * 8];
  }
}

// ---------------------------------------------------------------------------
// attn v3: NO LDS staging, NO hot-loop barriers. All MFMA operands gathered
// directly from global: A-frags (wk/wfc ∘ Aa) packed once per 32-row n-strip;
// B-frags (Ac rows) read per MFMA step — all 4 waves read the SAME 64-row
// B-group (L1-resident, 32 KB), each read feeds 2 MFMAs (S and G).
// Waves free-run; per-wave vmcnt stalls hidden by co-resident waves' MFMAs.
// blockIdx = k*64+g keeps the 8 k-replicas of (which,b) on one XCD.
// ---------------------------------------------------------------------------
__global__ __launch_bounds__(256, 2) void attn_kernel(
    const ushort* __restrict__ AT, const float* __restrict__ Watt,
    const float* __restrict__ Wfc, float* __restrict__ scoresK)
{
  const int idx = blockIdx.x;
  const int k = idx >> 6;
  const int g = idx & 63;
  const int which = g >> 5;
  const int b = g & 31;
  const int tid = threadIdx.x;
  const int wv = tid >> 6;
  const int lane = tid & 63;
  const int row32 = lane & 31;
  const int half32 = lane >> 5;

  const ushort* At_a = AT + (size_t)b * NN * HH;                       // anchor [n][h]
  const ushort* At_c = AT + ((size_t)(1 + which) * BB + b) * NN * HH;  // pos/neg [m][h]

  __shared__ __align__(16) float wkf[256];
  __shared__ __align__(16) float wff[256];
  __shared__ float red[8];

  wkf[tid] = Watt[(size_t)k * HH + tid];
  wff[tid] = Wfc[(size_t)k * HH + tid];
  __syncthreads();

  float num = 0.f, den = 0.f;

  for (int s = 0; s < 2; s++) {
    const int nbase = 128 * s + 32 * wv;
    // ---- pack A-frags for both variants, full K=256, held across m sweep
    bf16x8 saf[16], gaf[16];
    const ushort* arow = At_a + (size_t)(nbase + row32) * HH;
#pragma unroll
    for (int ks = 0; ks < 16; ks++) {
      const int off = 16 * ks + 8 * half32;
      const bf16x8 a = *(const bf16x8*)&arow[off];          // global, L2-hot
      const float4 wa = *(const float4*)&wkf[off];
      const float4 wb = *(const float4*)&wkf[off + 4];
      const float4 fa = *(const float4*)&wff[off];
      const float4 fb = *(const float4*)&wff[off + 4];
      const float w[8] = {wa.x, wa.y, wa.z, wa.w, wb.x, wb.y, wb.z, wb.w};
      const float f[8] = {fa.x, fa.y, fa.z, fa.w, fb.x, fb.y, fb.z, fb.w};
      union { bf16x8 v; unsigned u[4]; } sv, gv;
#pragma unroll
      for (int jj = 0; jj < 4; jj++) {
        const float a0 = bf2f((ushort)a[2 * jj]), a1 = bf2f((ushort)a[2 * jj + 1]);
        sv.u[jj] = pack2bf(a0 * w[2 * jj], a1 * w[2 * jj + 1]);
        gv.u[jj] = pack2bf(a0 * f[2 * jj], a1 * f[2 * jj + 1]);
      }
      saf[ks] = sv.v; gaf[ks] = gv.v;
    }

    for (int mc = 0; mc < 4; mc++) {
      // B rows 64*mc + row32 (+32): gathered straight from global (L1-hot)
      const ushort* Bbase = At_c + (size_t)(64 * mc + row32) * HH + 8 * half32;

      f32x16 aS0 = {0,0,0,0,0,0,0,0,0,0,0,0,0,0,0,0};
      f32x16 aS1 = {0,0,0,0,0,0,0,0,0,0,0,0,0,0,0,0};
      f32x16 aG0 = {0,0,0,0,0,0,0,0,0,0,0,0,0,0,0,0};
      f32x16 aG1 = {0,0,0,0,0,0,0,0,0,0,0,0,0,0,0,0};
#pragma unroll
      for (int ks = 0; ks < 16; ks++) {
        const bf16x8 b0 = *(const bf16x8*)&Bbase[16 * ks];
        const bf16x8 b1 = *(const bf16x8*)&Bbase[32 * HH + 16 * ks];
        aS0 = __builtin_amdgcn_mfma_f32_32x32x16_bf16(saf[ks], b0, aS0, 0, 0, 0);
        aG0 = __builtin_amdgcn_mfma_f32_32x32x16_bf16(gaf[ks], b0, aG0, 0, 0, 0);
        aS1 = __builtin_amdgcn_mfma_f32_32x32x16_bf16(saf[ks], b1, aS1, 0, 0, 0);
        aG1 = __builtin_amdgcn_mfma_f32_32x32x16_bf16(gaf[ks], b1, aG1, 0, 0, 0);
      }
#pragma unroll
      for (int r = 0; r < 16; r++) {
        const float p0 = __expf(aS0[r]);
        den += p0; num += p0 * aG0[r];
        const float p1 = __expf(aS1[r]);
        den += p1; num += p1 * aG1[r];
      }
    }
  }

  // reduce num/den: 64-lane butterfly, then 4 waves via LDS
#pragma unroll
  for (int off = 32; off >= 1; off >>= 1) {
    num += __shfl_xor(num, off);
    den += __shfl_xor(den, off);
  }
  if (lane == 0) { red[wv] = num; red[4 + wv] = den; }
  __syncthreads();
  if (tid == 0) {
    const float nt = red[0] + red[1] + red[2] + red[3];
    const float dt = red[4] + red[5] + red[6] + red[7];
    scoresK[idx] = nt / dt;
  }
}

// ---------------------------------------------------------------------------
__global__ __launch_bounds__(64) void loss_kernel(
    const float* __restrict__ scoresK, const float* __restrict__ bfc,
    float* __restrict__ out)
{
  const int tid = threadIdx.x;    // tid = which*32 + b
  float s = bfc[0];
#pragma unroll
  for (int k = 0; k < KK; k++) s += scoresK[k * 64 + tid];
  const float other = __shfl(s, tid + 32);
  float v = 0.f;
  if (tid < 32) v = fmaxf(other - s + MARGINF, 0.f);
#pragma unroll
  for (int off = 32; off >= 1; off >>= 1) v += __shfl_xor(v, off);
  if (tid == 0) out[0] = v * (1.0f / 32.0f);
}

// ---------------------------------------------------------------------------
extern "C" void kernel_launch(void* const* d_in, const int* in_sizes, int n_in,
                              void* d_out, int out_size, void* d_ws, size_t ws_size,
                              hipStream_t stream) {
  const float* he_a  = (const float*)d_in[0];
  const float* he_p  = (const float*)d_in[1];
  const float* he_n  = (const float*)d_in[2];
  const float* W_a2h = (const float*)d_in[3];
  const float* b_a2h = (const float*)d_in[4];
  const float* W_c2h = (const float*)d_in[5];
  const float* b_c2h = (const float*)d_in[6];
  const float* W_att = (const float*)d_in[7];
  // d_in[8] = b_att: cancels in global softmax
  const float* W_fc  = (const float*)d_in[9];
  const float* b_fc  = (const float*)d_in[10];

  ushort* AT = (ushort*)d_ws;                                // [3][B][N][H] bf16, 12.6 MB
  float* scoresK = (float*)(AT + (size_t)3 * BB * NN * HH);  // [512] fp32
  ushort* Wb = (ushort*)(scoresK + 512);                     // [2][256][320] bf16, 320 KB
  (void)ws_size; (void)in_sizes; (void)n_in; (void)out_size;

  wconv_kernel<<<640, 256, 0, stream>>>(W_a2h, W_c2h, Wb);
  dim3 pg(8, 96);
  proj_kernel<<<pg, 256, 0, stream>>>(he_a, he_p, he_n, Wb, b_a2h, b_c2h, AT);
  attn_kernel<<<512, 256, 0, stream>>>(AT, W_att, W_fc, scoresK);
  loss_kernel<<<1, 64, 0, stream>>>(scoresK, b_fc, (float*)d_out);
}

// Round 9
// 251.457 us; speedup vs baseline: 1.1825x; 1.1825x over previous
//
#include <hip/hip_runtime.h>

#define BB 32
#define NN 256
#define EE 300
#define HH 256
#define KK 8
#define MARGINF 0.2f
#define EP 320   // E padded for K-loop

typedef __attribute__((ext_vector_type(8))) short bf16x8;
typedef __attribute__((ext_vector_type(8))) _Float16 f16x8;
typedef __attribute__((ext_vector_type(4))) float f32x4;
typedef __attribute__((ext_vector_type(16))) float f32x16;

__device__ inline ushort f2bf(float f) {
  unsigned u = __float_as_uint(f);
  u += 0x7fffu + ((u >> 16) & 1u);          // RNE
  return (ushort)(u >> 16);
}
__device__ inline unsigned pack2bf(float f0, float f1) {   // [f0 lo | f1 hi], RNE
  unsigned u0 = __float_as_uint(f0); u0 += 0x7fffu + ((u0 >> 16) & 1u);
  unsigned u1 = __float_as_uint(f1); u1 += 0x7fffu + ((u1 >> 16) & 1u);
  return (u0 >> 16) | (u1 & 0xffff0000u);
}

// ---------------------------------------------------------------------------
// wconv: W_a2h/W_c2h fp32 [256][300] -> Wb bf16 [2][256][320] (zero-padded).
// ---------------------------------------------------------------------------
__global__ __launch_bounds__(256) void wconv_kernel(
    const float* __restrict__ Wa, const float* __restrict__ Wc,
    ushort* __restrict__ Wb)
{
  const int i = blockIdx.x * 256 + threadIdx.x;   // over 2*256*320 = 163840
  const int e = i % EP;
  const int hw = i / EP;
  const int h = hw & 255;
  const int w = hw >> 8;
  const float* src = w ? Wc : Wa;
  Wb[i] = (e < EE) ? f2bf(src[(size_t)h * EE + e]) : (ushort)0;
}

// ---------------------------------------------------------------------------
// proj (round-7 structure): one WG per (which,b,32-row n-tile), full H=256.
// X tile packed (bf16) to LDS once -> 1 barrier; W B-frags straight from
// L2-hot bf16 Wb. MFMA 16x16x32 bf16 (validated). Epilogue now emits FP16
// (more mantissa than bf16; attn consumes fp16).
// ---------------------------------------------------------------------------
__global__ __launch_bounds__(256, 3) void proj_kernel(
    const float* __restrict__ he_a, const float* __restrict__ he_p,
    const float* __restrict__ he_n, const ushort* __restrict__ Wb,
    const float* __restrict__ b_a2h, const float* __restrict__ b_c2h,
    _Float16* __restrict__ AT)
{
  const int z = blockIdx.y;           // 96 = 3*BB
  const int which = z >> 5;
  const int b = z & 31;
  const int n0 = blockIdx.x * 32;
  const int tid = threadIdx.x;
  const int wv = tid >> 6;
  const int lane = tid & 63;
  const int col = lane & 15;
  const int quad = lane >> 4;

  const float* X = (which == 0 ? he_a : which == 1 ? he_p : he_n) + (size_t)b * NN * EE;
  const ushort* W = Wb + (size_t)(which == 0 ? 0 : 1) * HH * EP;
  const float* bias = (which == 0 ? b_a2h : b_c2h);

  __shared__ __align__(16) ushort sX[32][328];
  __shared__ __align__(16) _Float16 tr[32][264];

  {
    const int row = tid >> 3, seg = tid & 7;
    const float* xr = X + (size_t)(n0 + row) * EE;
#pragma unroll
    for (int q = 0; q < 10; q++) {
      const int j = seg + 8 * q;
      float4 xv = {0.f, 0.f, 0.f, 0.f};
      if (j < 75) xv = *(const float4*)&xr[4 * j];
      uint2 p; p.x = pack2bf(xv.x, xv.y); p.y = pack2bf(xv.z, xv.w);
      *(uint2*)&sX[row][4 * j] = p;
    }
  }
  __syncthreads();

  f32x4 acc[2][4];
#pragma unroll
  for (int nf = 0; nf < 2; nf++)
#pragma unroll
    for (int mb = 0; mb < 4; mb++) acc[nf][mb] = (f32x4){0.f, 0.f, 0.f, 0.f};

#pragma unroll
  for (int ks = 0; ks < 10; ks++) {
    const int off = 32 * ks + 8 * quad;
    const bf16x8 a0 = *(const bf16x8*)&sX[col][off];
    const bf16x8 a1 = *(const bf16x8*)&sX[16 + col][off];
#pragma unroll
    for (int mb = 0; mb < 4; mb++) {
      const bf16x8 w8 = *(const bf16x8*)&W[(size_t)(64 * wv + 16 * mb + col) * EP + off];
      acc[0][mb] = __builtin_amdgcn_mfma_f32_16x16x32_bf16(a0, w8, acc[0][mb], 0, 0, 0);
      acc[1][mb] = __builtin_amdgcn_mfma_f32_16x16x32_bf16(a1, w8, acc[1][mb], 0, 0, 0);
    }
  }

#pragma unroll
  for (int nf = 0; nf < 2; nf++)
#pragma unroll
    for (int mb = 0; mb < 4; mb++) {
      const float bi = bias[64 * wv + 16 * mb + col];
#pragma unroll
      for (int r = 0; r < 4; r++)
        tr[16 * nf + 4 * quad + r][64 * wv + 16 * mb + col] = (_Float16)(acc[nf][mb][r] + bi);
    }
  __syncthreads();
  {
    const int row = tid >> 3, seg = tid & 7;
    _Float16* dst = &AT[((size_t)(which * BB + b) * NN + n0 + row) * HH];
#pragma unroll
    for (int j = 0; j < 4; j++)
      *(uint4*)&dst[(seg * 4 + j) * 8] = *(const uint4*)&tr[row][(seg * 4 + j) * 8];
  }
}

// ---------------------------------------------------------------------------
// attn v4: round-7 skeleton (LDS-staged B, padded, conflict-free) with
//  - fp16 operands: A-frag pack = v_pk_mul_f16 (4 ops/frag vs ~84 VALU bf16)
//  - mc-outer / strip-inner: 4 stagings per WG instead of 8
//  - register-prefetch of next Ac chunk issued before the MFMA block
//  - num/den split into 2 partials (shorter serial fp32 add chains)
// blockIdx = k*64+g keeps the 8 k-replicas of (which,b) on one XCD.
// ---------------------------------------------------------------------------
__global__ __launch_bounds__(256, 2) void attn_kernel(
    const _Float16* __restrict__ AT, const float* __restrict__ Watt,
    const float* __restrict__ Wfc, float* __restrict__ scoresK)
{
  const int idx = blockIdx.x;
  const int k = idx >> 6;
  const int g = idx & 63;
  const int which = g >> 5;
  const int b = g & 31;
  const int tid = threadIdx.x;
  const int wv = tid >> 6;
  const int lane = tid & 63;
  const int row32 = lane & 31;
  const int half32 = lane >> 5;

  const _Float16* At_a = AT + (size_t)b * NN * HH;                       // anchor [n][h]
  const _Float16* At_c = AT + ((size_t)(1 + which) * BB + b) * NN * HH;  // pos/neg [m][h]
  const uint4* Ac_u4 = (const uint4*)At_c;

  __shared__ __align__(16) _Float16 sAc[64][264];   // [m_local][h]
  __shared__ __align__(16) _Float16 wkh[256];
  __shared__ __align__(16) _Float16 wfh[256];
  __shared__ float red[8];

  wkh[tid] = (_Float16)Watt[(size_t)k * HH + tid];
  wfh[tid] = (_Float16)Wfc[(size_t)k * HH + tid];
  __syncthreads();

  float num0 = 0.f, den0 = 0.f, num1 = 0.f, den1 = 0.f;
  const int srow = tid >> 5, scol8 = (tid & 31) * 8;

  // prefetch Ac chunk 0 into regs
  uint4 pf[8];
#pragma unroll
  for (int q = 0; q < 8; q++)
    pf[q] = Ac_u4[(size_t)(q * 8 + srow) * 32 + (tid & 31)];

  for (int mc = 0; mc < 4; mc++) {
    __syncthreads();                 // prev chunk's B-frag reads done
#pragma unroll
    for (int q = 0; q < 8; q++)
      *(uint4*)&sAc[q * 8 + srow][scol8] = pf[q];
    __syncthreads();
    if (mc < 3) {                    // overlap next-chunk loads with compute
#pragma unroll
      for (int q = 0; q < 8; q++)
        pf[q] = Ac_u4[(size_t)(64 * (mc + 1) + q * 8 + srow) * 32 + (tid & 31)];
    }

#pragma unroll 1
    for (int s = 0; s < 2; s++) {
      const int nbase = 128 * s + 32 * wv;
      // pack A-frags (fp16 pk_mul): per ks 1 global b128 + 2 LDS b128 + 8 pk_mul
      f16x8 saf[16], gaf[16];
      const _Float16* arow = At_a + (size_t)(nbase + row32) * HH;
#pragma unroll
      for (int ks = 0; ks < 16; ks++) {
        const int off = 16 * ks + 8 * half32;
        const f16x8 a = *(const f16x8*)&arow[off];          // global, L2-hot
        const f16x8 w = *(const f16x8*)&wkh[off];
        const f16x8 f = *(const f16x8*)&wfh[off];
        saf[ks] = a * w;                                    // 4x v_pk_mul_f16
        gaf[ks] = a * f;
      }

      f32x16 aS0 = {0,0,0,0,0,0,0,0,0,0,0,0,0,0,0,0};
      f32x16 aS1 = {0,0,0,0,0,0,0,0,0,0,0,0,0,0,0,0};
      f32x16 aG0 = {0,0,0,0,0,0,0,0,0,0,0,0,0,0,0,0};
      f32x16 aG1 = {0,0,0,0,0,0,0,0,0,0,0,0,0,0,0,0};
#pragma unroll
      for (int ks = 0; ks < 16; ks++) {
        const int off = 16 * ks + 8 * half32;
        const f16x8 b0 = *(const f16x8*)&sAc[row32][off];
        const f16x8 b1 = *(const f16x8*)&sAc[32 + row32][off];
        aS0 = __builtin_amdgcn_mfma_f32_32x32x16_f16(saf[ks], b0, aS0, 0, 0, 0);
        aG0 = __builtin_amdgcn_mfma_f32_32x32x16_f16(gaf[ks], b0, aG0, 0, 0, 0);
        aS1 = __builtin_amdgcn_mfma_f32_32x32x16_f16(saf[ks], b1, aS1, 0, 0, 0);
        aG1 = __builtin_amdgcn_mfma_f32_32x32x16_f16(gaf[ks], b1, aG1, 0, 0, 0);
      }
#pragma unroll
      for (int r = 0; r < 16; r += 2) {
        const float p0a = __expf(aS0[r]);
        den0 += p0a; num0 += p0a * aG0[r];
        const float p0b = __expf(aS0[r + 1]);
        den1 += p0b; num1 += p0b * aG0[r + 1];
        const float p1a = __expf(aS1[r]);
        den0 += p1a; num0 += p1a * aG1[r];
        const float p1b = __expf(aS1[r + 1]);
        den1 += p1b; num1 += p1b * aG1[r + 1];
      }
    }
  }

  float num = num0 + num1, den = den0 + den1;
#pragma unroll
  for (int off = 32; off >= 1; off >>= 1) {
    num += __shfl_xor(num, off);
    den += __shfl_xor(den, off);
  }
  if (lane == 0) { red[wv] = num; red[4 + wv] = den; }
  __syncthreads();
  if (tid == 0) {
    const float nt = red[0] + red[1] + red[2] + red[3];
    const float dt = red[4] + red[5] + red[6] + red[7];
    scoresK[idx] = nt / dt;
  }
}

// ---------------------------------------------------------------------------
__global__ __launch_bounds__(64) void loss_kernel(
    const float* __restrict__ scoresK, const float* __restrict__ bfc,
    float* __restrict__ out)
{
  const int tid = threadIdx.x;    // tid = which*32 + b
  float s = bfc[0];
#pragma unroll
  for (int k = 0; k < KK; k++) s += scoresK[k * 64 + tid];
  const float other = __shfl(s, tid + 32);
  float v = 0.f;
  if (tid < 32) v = fmaxf(other - s + MARGINF, 0.f);
#pragma unroll
  for (int off = 32; off >= 1; off >>= 1) v += __shfl_xor(v, off);
  if (tid == 0) out[0] = v * (1.0f / 32.0f);
}

// ---------------------------------------------------------------------------
extern "C" void kernel_launch(void* const* d_in, const int* in_sizes, int n_in,
                              void* d_out, int out_size, void* d_ws, size_t ws_size,
                              hipStream_t stream) {
  const float* he_a  = (const float*)d_in[0];
  const float* he_p  = (const float*)d_in[1];
  const float* he_n  = (const float*)d_in[2];
  const float* W_a2h = (const float*)d_in[3];
  const float* b_a2h = (const float*)d_in[4];
  const float* W_c2h = (const float*)d_in[5];
  const float* b_c2h = (const float*)d_in[6];
  const float* W_att = (const float*)d_in[7];
  // d_in[8] = b_att: cancels in global softmax
  const float* W_fc  = (const float*)d_in[9];
  const float* b_fc  = (const float*)d_in[10];

  _Float16* AT = (_Float16*)d_ws;                            // [3][B][N][H] fp16, 12.6 MB
  float* scoresK = (float*)(AT + (size_t)3 * BB * NN * HH);  // [512] fp32
  ushort* Wb = (ushort*)(scoresK + 512);                     // [2][256][320] bf16, 320 KB
  (void)ws_size; (void)in_sizes; (void)n_in; (void)out_size;

  wconv_kernel<<<640, 256, 0, stream>>>(W_a2h, W_c2h, Wb);
  dim3 pg(8, 96);
  proj_kernel<<<pg, 256, 0, stream>>>(he_a, he_p, he_n, Wb, b_a2h, b_c2h, AT);
  attn_kernel<<<512, 256, 0, stream>>>(AT, W_att, W_fc, scoresK);
  loss_kernel<<<1, 64, 0, stream>>>(scoresK, b_fc, (float*)d_out);
}

// Round 10
// 148.775 us; speedup vs baseline: 1.9987x; 1.6902x over previous
//
#include <hip/hip_runtime.h>

#define BB 32
#define NN 256
#define EE 300
#define HH 256
#define KK 8
#define MARGINF 0.2f
#define EP 320   // E padded for K-loop

typedef __attribute__((ext_vector_type(8))) short bf16x8;
typedef __attribute__((ext_vector_type(8))) _Float16 f16x8;
typedef __attribute__((ext_vector_type(4))) float f32x4;
typedef __attribute__((ext_vector_type(16))) float f32x16;

__device__ inline ushort f2bf(float f) {
  unsigned u = __float_as_uint(f);
  u += 0x7fffu + ((u >> 16) & 1u);          // RNE
  return (ushort)(u >> 16);
}
__device__ inline unsigned pack2bf(float f0, float f1) {   // [f0 lo | f1 hi], RNE
  unsigned u0 = __float_as_uint(f0); u0 += 0x7fffu + ((u0 >> 16) & 1u);
  unsigned u1 = __float_as_uint(f1); u1 += 0x7fffu + ((u1 >> 16) & 1u);
  return (u0 >> 16) | (u1 & 0xffff0000u);
}

// ---------------------------------------------------------------------------
// wconv: W fp32 -> bf16 [2][256][320] (zero-padded) + zero numden[1024]
// (extra block 640; numden is accumulated by attn via atomics).
// ---------------------------------------------------------------------------
__global__ __launch_bounds__(256) void wconv_kernel(
    const float* __restrict__ Wa, const float* __restrict__ Wc,
    ushort* __restrict__ Wb, float* __restrict__ numden)
{
  if (blockIdx.x == 640) {
    const int t = threadIdx.x;
#pragma unroll
    for (int i = 0; i < 4; i++) numden[t * 4 + i] = 0.f;
    return;
  }
  const int i = blockIdx.x * 256 + threadIdx.x;   // over 2*256*320 = 163840
  const int e = i % EP;
  const int hw = i / EP;
  const int h = hw & 255;
  const int w = hw >> 8;
  const float* src = w ? Wc : Wa;
  Wb[i] = (e < EE) ? f2bf(src[(size_t)h * EE + e]) : (ushort)0;
}

// ---------------------------------------------------------------------------
// proj (unchanged round-9 version, emits fp16): one WG per (which,b,32-row
// n-tile), X packed to LDS once, W B-frags from L2-hot bf16 Wb.
// ---------------------------------------------------------------------------
__global__ __launch_bounds__(256, 3) void proj_kernel(
    const float* __restrict__ he_a, const float* __restrict__ he_p,
    const float* __restrict__ he_n, const ushort* __restrict__ Wb,
    const float* __restrict__ b_a2h, const float* __restrict__ b_c2h,
    _Float16* __restrict__ AT)
{
  const int z = blockIdx.y;           // 96 = 3*BB
  const int which = z >> 5;
  const int b = z & 31;
  const int n0 = blockIdx.x * 32;
  const int tid = threadIdx.x;
  const int wv = tid >> 6;
  const int lane = tid & 63;
  const int col = lane & 15;
  const int quad = lane >> 4;

  const float* X = (which == 0 ? he_a : which == 1 ? he_p : he_n) + (size_t)b * NN * EE;
  const ushort* W = Wb + (size_t)(which == 0 ? 0 : 1) * HH * EP;
  const float* bias = (which == 0 ? b_a2h : b_c2h);

  __shared__ __align__(16) ushort sX[32][328];
  __shared__ __align__(16) _Float16 tr[32][264];

  {
    const int row = tid >> 3, seg = tid & 7;
    const float* xr = X + (size_t)(n0 + row) * EE;
#pragma unroll
    for (int q = 0; q < 10; q++) {
      const int j = seg + 8 * q;
      float4 xv = {0.f, 0.f, 0.f, 0.f};
      if (j < 75) xv = *(const float4*)&xr[4 * j];
      uint2 p; p.x = pack2bf(xv.x, xv.y); p.y = pack2bf(xv.z, xv.w);
      *(uint2*)&sX[row][4 * j] = p;
    }
  }
  __syncthreads();

  f32x4 acc[2][4];
#pragma unroll
  for (int nf = 0; nf < 2; nf++)
#pragma unroll
    for (int mb = 0; mb < 4; mb++) acc[nf][mb] = (f32x4){0.f, 0.f, 0.f, 0.f};

#pragma unroll
  for (int ks = 0; ks < 10; ks++) {
    const int off = 32 * ks + 8 * quad;
    const bf16x8 a0 = *(const bf16x8*)&sX[col][off];
    const bf16x8 a1 = *(const bf16x8*)&sX[16 + col][off];
#pragma unroll
    for (int mb = 0; mb < 4; mb++) {
      const bf16x8 w8 = *(const bf16x8*)&W[(size_t)(64 * wv + 16 * mb + col) * EP + off];
      acc[0][mb] = __builtin_amdgcn_mfma_f32_16x16x32_bf16(a0, w8, acc[0][mb], 0, 0, 0);
      acc[1][mb] = __builtin_amdgcn_mfma_f32_16x16x32_bf16(a1, w8, acc[1][mb], 0, 0, 0);
    }
  }

#pragma unroll
  for (int nf = 0; nf < 2; nf++)
#pragma unroll
    for (int mb = 0; mb < 4; mb++) {
      const float bi = bias[64 * wv + 16 * mb + col];
#pragma unroll
      for (int r = 0; r < 4; r++)
        tr[16 * nf + 4 * quad + r][64 * wv + 16 * mb + col] = (_Float16)(acc[nf][mb][r] + bi);
    }
  __syncthreads();
  {
    const int row = tid >> 3, seg = tid & 7;
    _Float16* dst = &AT[((size_t)(which * BB + b) * NN + n0 + row) * HH];
#pragma unroll
    for (int j = 0; j < 4; j++)
      *(uint4*)&dst[(seg * 4 + j) * 8] = *(const uint4*)&tr[row][(seg * 4 + j) * 8];
  }
}

// ---------------------------------------------------------------------------
// attn v5: one WG per (which,b,n-quarter), ALL 8 heads fused.
// Stage FULL Ac (256x264 fp16, 135 KB) + all Watt/Wfc rows ONCE -> single
// barrier; then k-loop free-runs with zero barriers. Wave roles: strip=wv&1
// (32 n-rows of the quarter), mh=wv>>1 (128 m-rows). A-packs via v_pk_mul_f16
// from L1-resident Aa strip; B from LDS; 32x32x16 f16 MFMA; exp+reduce;
// per-(g,k) num/den accumulated with device-scope atomicAdd (numden zeroed
// by wconv). Register budget = round-7-proven 128 VGPR + 64 acc, no extras.
// blockIdx = q*64 + g -> %8 = g%8 keeps q-replicas of (which,b) on one XCD.
// ---------------------------------------------------------------------------
__global__ __launch_bounds__(256, 1) void attn_kernel(
    const _Float16* __restrict__ AT, const float* __restrict__ Watt,
    const float* __restrict__ Wfc, float* __restrict__ numden)
{
  const int idx = blockIdx.x;        // q*64 + g
  const int q = idx >> 6;
  const int g = idx & 63;
  const int which = g >> 5;
  const int b = g & 31;
  const int tid = threadIdx.x;
  const int wv = tid >> 6;
  const int lane = tid & 63;
  const int row32 = lane & 31;
  const int half32 = lane >> 5;
  const int strip = wv & 1;
  const int mh = wv >> 1;

  const _Float16* At_a = AT + (size_t)b * NN * HH;                       // anchor [n][h]
  const _Float16* At_c = AT + ((size_t)(1 + which) * BB + b) * NN * HH;  // pos/neg [m][h]
  const uint4* Ac_u4 = (const uint4*)At_c;

  __shared__ __align__(16) _Float16 sAc[256][264];   // 135 KB
  __shared__ __align__(16) _Float16 wkh[8][256];
  __shared__ __align__(16) _Float16 wfh[8][256];

  // ---- stage: full Ac (8192 uint4, 32/thread) + weight rows
  const int srow = tid >> 5, scol8 = (tid & 31) * 8;
#pragma unroll
  for (int t = 0; t < 32; t++)
    *(uint4*)&sAc[8 * t + srow][scol8] = Ac_u4[(size_t)(8 * t + srow) * 32 + (tid & 31)];
#pragma unroll
  for (int kk = 0; kk < KK; kk++) {
    wkh[kk][tid] = (_Float16)Watt[kk * HH + tid];
    wfh[kk][tid] = (_Float16)Wfc[kk * HH + tid];
  }
  __syncthreads();   // the ONLY barrier

  const int nbase = 64 * q + 32 * strip;
  const _Float16* arow = At_a + (size_t)(nbase + row32) * HH;  // L1-resident (16 KB/wave)

#pragma unroll 1
  for (int kk = 0; kk < KK; kk++) {
    // A-frags for this head: (wk .* Aa) and (wfc .* Aa), K=256
    f16x8 saf[16], gaf[16];
#pragma unroll
    for (int ks = 0; ks < 16; ks++) {
      const int off = 16 * ks + 8 * half32;
      const f16x8 a = *(const f16x8*)&arow[off];
      const f16x8 w = *(const f16x8*)&wkh[kk][off];
      const f16x8 f = *(const f16x8*)&wfh[kk][off];
      saf[ks] = a * w;                 // v_pk_mul_f16 x4
      gaf[ks] = a * f;
    }

    float num = 0.f, den = 0.f;
#pragma unroll 1                       // one 64-row chunk's accs live at a time
    for (int mc = 0; mc < 2; mc++) {
      const int mbase = 128 * mh + 64 * mc;
      f32x16 aS0 = {0,0,0,0,0,0,0,0,0,0,0,0,0,0,0,0};
      f32x16 aS1 = {0,0,0,0,0,0,0,0,0,0,0,0,0,0,0,0};
      f32x16 aG0 = {0,0,0,0,0,0,0,0,0,0,0,0,0,0,0,0};
      f32x16 aG1 = {0,0,0,0,0,0,0,0,0,0,0,0,0,0,0,0};
#pragma unroll
      for (int ks = 0; ks < 16; ks++) {
        const int off = 16 * ks + 8 * half32;
        const f16x8 b0 = *(const f16x8*)&sAc[mbase + row32][off];
        const f16x8 b1 = *(const f16x8*)&sAc[mbase + 32 + row32][off];
        aS0 = __builtin_amdgcn_mfma_f32_32x32x16_f16(saf[ks], b0, aS0, 0, 0, 0);
        aG0 = __builtin_amdgcn_mfma_f32_32x32x16_f16(gaf[ks], b0, aG0, 0, 0, 0);
        aS1 = __builtin_amdgcn_mfma_f32_32x32x16_f16(saf[ks], b1, aS1, 0, 0, 0);
        aG1 = __builtin_amdgcn_mfma_f32_32x32x16_f16(gaf[ks], b1, aG1, 0, 0, 0);
      }
#pragma unroll
      for (int r = 0; r < 16; r++) {
        const float p0 = __expf(aS0[r]);
        den += p0; num += p0 * aG0[r];
        const float p1 = __expf(aS1[r]);
        den += p1; num += p1 * aG1[r];
      }
    }

    // wave butterfly, then one atomic pair per wave
#pragma unroll
    for (int off = 32; off >= 1; off >>= 1) {
      num += __shfl_xor(num, off);
      den += __shfl_xor(den, off);
    }
    if (lane == 0) {
      atomicAdd(&numden[(g * KK + kk) * 2 + 0], num);
      atomicAdd(&numden[(g * KK + kk) * 2 + 1], den);
    }
  }
}

// ---------------------------------------------------------------------------
// loss: score(g) = b_fc + sum_k num[g,k]/den[g,k];  mean_b relu(sn-sp+margin)
// ---------------------------------------------------------------------------
__global__ __launch_bounds__(64) void loss_kernel(
    const float* __restrict__ numden, const float* __restrict__ bfc,
    float* __restrict__ out)
{
  const int tid = threadIdx.x;    // tid = g = which*32 + b
  float s = bfc[0];
#pragma unroll
  for (int k = 0; k < KK; k++)
    s += numden[(tid * KK + k) * 2] / numden[(tid * KK + k) * 2 + 1];
  const float other = __shfl(s, tid + 32);
  float v = 0.f;
  if (tid < 32) v = fmaxf(other - s + MARGINF, 0.f);
#pragma unroll
  for (int off = 32; off >= 1; off >>= 1) v += __shfl_xor(v, off);
  if (tid == 0) out[0] = v * (1.0f / 32.0f);
}

// ---------------------------------------------------------------------------
extern "C" void kernel_launch(void* const* d_in, const int* in_sizes, int n_in,
                              void* d_out, int out_size, void* d_ws, size_t ws_size,
                              hipStream_t stream) {
  const float* he_a  = (const float*)d_in[0];
  const float* he_p  = (const float*)d_in[1];
  const float* he_n  = (const float*)d_in[2];
  const float* W_a2h = (const float*)d_in[3];
  const float* b_a2h = (const float*)d_in[4];
  const float* W_c2h = (const float*)d_in[5];
  const float* b_c2h = (const float*)d_in[6];
  const float* W_att = (const float*)d_in[7];
  // d_in[8] = b_att: cancels in global softmax
  const float* W_fc  = (const float*)d_in[9];
  const float* b_fc  = (const float*)d_in[10];

  _Float16* AT = (_Float16*)d_ws;                            // [3][B][N][H] fp16, 12.6 MB
  ushort* Wb = (ushort*)(AT + (size_t)3 * BB * NN * HH);     // [2][256][320] bf16, 320 KB
  float* numden = (float*)(Wb + (size_t)2 * HH * EP);        // [64][8][2] fp32, 4 KB
  (void)ws_size; (void)in_sizes; (void)n_in; (void)out_size;

  wconv_kernel<<<641, 256, 0, stream>>>(W_a2h, W_c2h, Wb, numden);
  dim3 pg(8, 96);
  proj_kernel<<<pg, 256, 0, stream>>>(he_a, he_p, he_n, Wb, b_a2h, b_c2h, AT);
  attn_kernel<<<256, 256, 0, stream>>>(AT, W_att, W_fc, numden);
  loss_kernel<<<1, 64, 0, stream>>>(numden, b_fc, (float*)d_out);
}